// Round 2
// baseline (8805.913 us; speedup 1.0000x reference)
//
#include <hip/hip_runtime.h>
#include <hip/hip_bf16.h>

typedef __hip_bfloat16 bf16;
typedef short s16x8 __attribute__((ext_vector_type(8)));
typedef float f32x4 __attribute__((ext_vector_type(4)));

#define DIM   1536
#define HEADS 24
#define HD    64
#define TOTAL 3072
#define ENCR  384
#define INNER 6144
#define SIX   9216

// ---- dtype-agnostic loads: flag==1 -> inputs are float32, flag==0 -> bf16
__device__ __forceinline__ float ldf(const void* p, size_t i, int f) {
    return f ? ((const float*)p)[i]
             : __bfloat162float(((const bf16*)p)[i]);
}
__device__ __forceinline__ short f2s(float v) {
    bf16 b = __float2bfloat16(v);
    short s; __builtin_memcpy(&s, &b, 2); return s;
}
__device__ __forceinline__ s16x8 ldb8(const void* B, size_t i, int f) {
    s16x8 r;
    if (f) {
        const float4* p = (const float4*)((const float*)B + i);
        float4 x = p[0], y = p[1];
        r[0]=f2s(x.x); r[1]=f2s(x.y); r[2]=f2s(x.z); r[3]=f2s(x.w);
        r[4]=f2s(y.x); r[5]=f2s(y.y); r[6]=f2s(y.z); r[7]=f2s(y.w);
    } else {
        r = *(const s16x8*)((const short*)B + i);
    }
    return r;
}

// ---------------- probe: detect input dtype. bf16 weight data has no exp==0xFF
// patterns; float32 read as shorts has ~0.4% in the mantissa halves.
__global__ __launch_bounds__(256) void probe_kernel(const unsigned short* __restrict__ w,
                                                    int* __restrict__ flag) {
    __shared__ int cnt;
    if (threadIdx.x == 0) cnt = 0;
    __syncthreads();
    int local = 0;
    for (int i = threadIdx.x; i < 65536; i += 256) {
        unsigned short u = w[i];
        if (((u >> 7) & 0xFF) == 0xFF) local++;
    }
    atomicAdd(&cnt, local);
    __syncthreads();
    if (threadIdx.x == 0) flag[0] = (cnt > 0) ? 1 : 0;
}

// ---------------------------------------------------------------- silu(temb)
__global__ __launch_bounds__(256) void silu_kernel(const void* __restrict__ temb,
                                                   float* __restrict__ sact,
                                                   const int* __restrict__ flag) {
    int f = flag[0];
    int i = blockIdx.x * 256 + threadIdx.x;   // grid exact: 3*1536
    float x = ldf(temb, i, f);
    sact[i] = x / (1.f + __expf(-x));
}

// -------------------------------------------- e6 = silu(temb) @ W + b (3x9216)
__global__ __launch_bounds__(256) void ada_kernel(const float* __restrict__ sact,
                                                  const void* __restrict__ W,
                                                  const void* __restrict__ bias,
                                                  float* __restrict__ out,
                                                  const int* __restrict__ flag) {
    int f = flag[0];
    __shared__ float red[3][4][64];
    int c   = threadIdx.x & 63;
    int col = blockIdx.x * 64 + c;
    int kq  = threadIdx.x >> 6;
    float a0 = 0.f, a1 = 0.f, a2 = 0.f;
    for (int k = kq * 384; k < kq * 384 + 384; ++k) {
        float wv = ldf(W, (size_t)k * SIX + col, f);
        a0 += sact[k] * wv;
        a1 += sact[1536 + k] * wv;
        a2 += sact[3072 + k] * wv;
    }
    red[0][kq][c] = a0; red[1][kq][c] = a1; red[2][kq][c] = a2;
    __syncthreads();
    if (kq < 3) {
        float s = red[kq][0][c] + red[kq][1][c] + red[kq][2][c] + red[kq][3][c]
                + ldf(bias, col, f);
        out[(size_t)kq * SIX + col] = s;
    }
}

// ------------------------- LayerNorm + AdaLN modulate: out = LN(x)*(1+scale)+shift
__global__ __launch_bounds__(256) void ln_mod_kernel(const void* __restrict__ x,
                                                     const float* __restrict__ ada,
                                                     bf16* __restrict__ out,
                                                     int shift_sel, int scale_sel,
                                                     int is_enc, int x_dual,
                                                     const int* __restrict__ flag) {
    int f = x_dual ? flag[0] : 0;
    __shared__ float r1[256], r2[256];
    int t = blockIdx.x, tid = threadIdx.x;
    int stage = is_enc ? (t >> 7) : (t < 512 ? 0 : (t < 1536 ? 1 : 2));
    float v[6]; float s = 0.f, s2 = 0.f;
#pragma unroll
    for (int i = 0; i < 6; ++i) {
        float a = ldf(x, (size_t)t * DIM + tid + i * 256, f);
        v[i] = a; s += a; s2 += a * a;
    }
    r1[tid] = s; r2[tid] = s2;
    __syncthreads();
    for (int st = 128; st; st >>= 1) {
        if (tid < st) { r1[tid] += r1[tid + st]; r2[tid] += r2[tid + st]; }
        __syncthreads();
    }
    float mean = r1[0] * (1.f / 1536.f);
    float var  = fmaxf(r2[0] * (1.f / 1536.f) - mean * mean, 0.f);
    float inv  = rsqrtf(var + 1e-6f);
    const float* ab = ada + (size_t)stage * SIX;
#pragma unroll
    for (int i = 0; i < 6; ++i) {
        int c = tid + i * 256;
        float sc = ab[scale_sel * DIM + c];
        float sh = ab[shift_sel * DIM + c];
        out[(size_t)t * DIM + c] = __float2bfloat16((v[i] - mean) * inv * (1.f + sc) + sh);
    }
}

// ---------------------------------------------------------------- MFMA GEMM
// C[M,N] = act(A[M,K] @ B[K,N] + bias). A is ws bf16; B/bias are inputs (dual).
#define LDK 48
__global__ __launch_bounds__(256) void gemm_kernel(const short* __restrict__ A,
                                                   const void* __restrict__ B,
                                                   const void* __restrict__ bias,
                                                   bf16* __restrict__ C,
                                                   int M, int N, int K, int act,
                                                   const int* __restrict__ flag) {
    int f = flag[0];
    __shared__ __align__(16) short As[128 * LDK];
    __shared__ __align__(16) short Bs[128 * LDK];
    int tid = threadIdx.x;
    int lane = tid & 63, wid = tid >> 6;
    int wy = wid >> 1, wx = wid & 1;
    int m16 = lane & 15, quad = lane >> 4;
    int m0 = blockIdx.y * 128, n0 = blockIdx.x * 128;

    int ar0 = tid >> 2;
    int ac  = (tid & 3) * 8;
    int br0 = tid >> 4;
    int bc  = (tid & 15) * 8;

    f32x4 acc[4][4] = {};

    for (int k0 = 0; k0 < K; k0 += 32) {
        s16x8 a0 = *(const s16x8*)(A + (size_t)(m0 + ar0) * K + k0 + ac);
        s16x8 a1 = *(const s16x8*)(A + (size_t)(m0 + ar0 + 64) * K + k0 + ac);
        s16x8 b0 = ldb8(B, (size_t)(k0 + br0) * N + n0 + bc, f);
        s16x8 b1 = ldb8(B, (size_t)(k0 + br0 + 16) * N + n0 + bc, f);
        __syncthreads();
        *(s16x8*)(&As[ar0 * LDK + ac]) = a0;
        *(s16x8*)(&As[(ar0 + 64) * LDK + ac]) = a1;
#pragma unroll
        for (int i = 0; i < 8; ++i) {          // transpose B into Bs[n][k]
            Bs[(bc + i) * LDK + br0] = b0[i];
            Bs[(bc + i) * LDK + br0 + 16] = b1[i];
        }
        __syncthreads();
        s16x8 af[4], bfr[4];
#pragma unroll
        for (int i = 0; i < 4; ++i) {
            af[i]  = *(const s16x8*)(&As[(wy * 64 + i * 16 + m16) * LDK + quad * 8]);
            bfr[i] = *(const s16x8*)(&Bs[(wx * 64 + i * 16 + m16) * LDK + quad * 8]);
        }
#pragma unroll
        for (int im = 0; im < 4; ++im)
#pragma unroll
            for (int in = 0; in < 4; ++in)
                acc[im][in] = __builtin_amdgcn_mfma_f32_16x16x32_bf16(
                    af[im], bfr[in], acc[im][in], 0, 0, 0);
    }

#pragma unroll
    for (int in = 0; in < 4; ++in) {
        int gn = n0 + wx * 64 + in * 16 + m16;
        float bsv = ldf(bias, gn, f);
#pragma unroll
        for (int im = 0; im < 4; ++im) {
#pragma unroll
            for (int r = 0; r < 4; ++r) {
                int gm = m0 + wy * 64 + im * 16 + quad * 4 + r;
                float v = acc[im][in][r] + bsv;
                if (act == 1) {
                    float xx = v;
                    v = 0.5f * xx * (1.f + tanhf(0.7978845608028654f *
                                                 (xx + 0.044715f * xx * xx * xx)));
                }
                C[(size_t)gm * N + gn] = __float2bfloat16(v);
            }
        }
    }
}

// -------------------------------------- per-(token,head) RMSNorm over 64, in-place
__global__ __launch_bounds__(256) void rms_kernel(bf16* __restrict__ x,
                                                  const void* __restrict__ w,
                                                  const int* __restrict__ flag) {
    int f = flag[0];
    int g = blockIdx.x * 4 + (threadIdx.x >> 6);
    int lane = threadIdx.x & 63;
    float v = __bfloat162float(x[(size_t)g * 64 + lane]);
    float ss = v * v;
#pragma unroll
    for (int off = 32; off; off >>= 1) ss += __shfl_xor(ss, off);
    float inv = rsqrtf(ss * (1.f / 64.f) + 1e-6f);
    x[(size_t)g * 64 + lane] = __float2bfloat16(v * inv * ldf(w, lane, f));
}

// ----------------------------------------------------- rotation-matrix RoPE in-place
__global__ __launch_bounds__(256) void rope_kernel(bf16* __restrict__ x,
                                                   const void* __restrict__ r0,
                                                   const void* __restrict__ r1,
                                                   const void* __restrict__ r2,
                                                   int is_enc,
                                                   const int* __restrict__ flag) {
    int f = flag[0];
    int gid = blockIdx.x * 256 + threadIdx.x;   // exact: ntok*24*32
    int d2 = gid & 31;
    int th = gid >> 5;
    int h = th % 24;
    int t = th / 24;
    int stage, pos;
    if (is_enc) { stage = t >> 7; pos = t & 127; }
    else if (t < 512)  { stage = 0; pos = 128 + t; }
    else if (t < 1536) { stage = 1; pos = 128 + t - 512; }
    else               { stage = 2; pos = 128 + t - 1536; }
    const void* rt = stage == 0 ? r0 : (stage == 1 ? r1 : r2);
    size_t ro = ((size_t)pos * 32 + d2) * 4;
    float c00 = ldf(rt, ro + 0, f);
    float c01 = ldf(rt, ro + 1, f);
    float c10 = ldf(rt, ro + 2, f);
    float c11 = ldf(rt, ro + 3, f);
    size_t i0 = ((size_t)t * 24 + h) * 64 + d2 * 2;
    float x0 = __bfloat162float(x[i0]), x1 = __bfloat162float(x[i0 + 1]);
    x[i0]     = __float2bfloat16(c00 * x0 + c01 * x1);
    x[i0 + 1] = __float2bfloat16(c10 * x0 + c11 * x1);
}

// ----------------------------------------------- flash attention, wave per (q,h)
__global__ __launch_bounds__(256) void attn_kernel(const bf16* __restrict__ Qb,
                                                   const bf16* __restrict__ Kb,
                                                   const bf16* __restrict__ Vb,
                                                   const bf16* __restrict__ EQ,
                                                   const bf16* __restrict__ EK,
                                                   const bf16* __restrict__ EV,
                                                   const int* __restrict__ encv,
                                                   bf16* __restrict__ AH,
                                                   bf16* __restrict__ AE) {
    int tid = threadIdx.x, wid = tid >> 6, lane = tid & 63;
    int b = blockIdx.x;
    int h = b % 24;
    int gq = b / 24;
    int s, qg, S, hbase;
    if (gq < 160)      { s = 0; qg = gq;       S = 640;  hbase = 0; }
    else if (gq < 448) { s = 1; qg = gq - 160; S = 1152; hbase = 512; }
    else               { s = 2; qg = gq - 448; S = 1664; hbase = 1536; }
    int q = qg * 4 + wid;

    const bf16* qptr = (q < 128)
        ? EQ + ((size_t)(s * 128 + q) * DIM + h * HD)
        : Qb + ((size_t)(hbase + q - 128) * DIM + h * HD);
    float qv = __bfloat162float(qptr[lane]) * 0.125f;   // fold SCALE
    float qf[64];
#pragma unroll
    for (int d = 0; d < 64; ++d) qf[d] = __shfl(qv, d);

    int ev = encv[s];
    float mrun = -1e30f, lrun = 0.f, orun = 0.f;
    int nkb = S >> 6;
    for (int kb = 0; kb < nkb; ++kb) {
        int j = kb * 64 + lane;
        bool valid = (j >= 128) || (j < ev);
        const bf16* kr = (j < 128)
            ? EK + ((size_t)(s * 128 + j) * DIM + h * HD)
            : Kb + ((size_t)(hbase + j - 128) * DIM + h * HD);
        const uint4* kr4 = (const uint4*)kr;
        float acc = 0.f;
#pragma unroll
        for (int c = 0; c < 8; ++c) {
            uint4 kv = kr4[c];
            const unsigned int* kw = (const unsigned int*)&kv;
#pragma unroll
            for (int u = 0; u < 4; ++u) {
                union { unsigned int i; float fl; } lo, hi;
                lo.i = kw[u] << 16; hi.i = kw[u] & 0xffff0000u;
                acc += qf[c * 8 + u * 2] * lo.fl;
                acc += qf[c * 8 + u * 2 + 1] * hi.fl;
            }
        }
        float sc = valid ? acc : -1e30f;
        float bm = sc;
#pragma unroll
        for (int off = 32; off; off >>= 1) bm = fmaxf(bm, __shfl_xor(bm, off));
        if (bm > -1e29f) {
            float mn = fmaxf(mrun, bm);
            float alpha = __expf(mrun - mn);
            float p = valid ? __expf(sc - mn) : 0.f;
            float psum = p;
#pragma unroll
            for (int off = 32; off; off >>= 1) psum += __shfl_xor(psum, off);
            float oacc = 0.f;
            for (int jj = 0; jj < 64; ++jj) {
                float pj = __shfl(p, jj);
                if (pj != 0.f) {
                    int jg = kb * 64 + jj;
                    const bf16* vr = (jg < 128)
                        ? EV + ((size_t)(s * 128 + jg) * DIM + h * HD)
                        : Vb + ((size_t)(hbase + jg - 128) * DIM + h * HD);
                    oacc += pj * __bfloat162float(vr[lane]);
                }
            }
            orun = orun * alpha + oacc;
            lrun = lrun * alpha + psum;
            mrun = mn;
        }
    }
    float outv = orun / fmaxf(lrun, 1e-37f);
    bf16* op = (q < 128)
        ? AE + ((size_t)(s * 128 + q) * DIM + h * HD)
        : AH + ((size_t)(hbase + q - 128) * DIM + h * HD);
    op[lane] = __float2bfloat16(outv);
}

// --------------------- out = base + gate[stage]*delta; base/out may be input/output
__global__ __launch_bounds__(256) void resid_kernel(const void* __restrict__ base,
                                                    const bf16* __restrict__ delta,
                                                    const float* __restrict__ ada,
                                                    int gate_sel, int is_enc,
                                                    void* __restrict__ out,
                                                    size_t out_off,
                                                    int base_dual, int out_dual,
                                                    const int* __restrict__ flag) {
    int bfl = base_dual ? flag[0] : 0;
    int ofl = out_dual ? flag[0] : 0;
    int gid = blockIdx.x * 256 + threadIdx.x;   // exact grid
    int t = gid / DIM, c = gid - t * DIM;
    int stage = is_enc ? (t >> 7) : (t < 512 ? 0 : (t < 1536 ? 1 : 2));
    float g = ada[(size_t)stage * SIX + gate_sel * DIM + c];
    float v = ldf(base, gid, bfl) + g * __bfloat162float(delta[gid]);
    if (ofl) ((float*)out)[out_off + gid] = v;
    else     ((bf16*)out)[out_off + gid] = __float2bfloat16(v);
}

extern "C" void kernel_launch(void* const* d_in, const int* in_sizes, int n_in,
                              void* d_out, int out_size, void* d_ws, size_t ws_size,
                              hipStream_t stream) {
    (void)in_sizes; (void)n_in; (void)out_size; (void)ws_size;
    const void* hid   = d_in[0];
    const void* enc   = d_in[1];
    const void* temb  = d_in[2];
    const int*  encv  = (const int*)d_in[3];
    const void* rope0 = d_in[4];
    const void* rope1 = d_in[5];
    const void* rope2 = d_in[6];
    const void* ada_w = d_in[7];  const void* ada_b = d_in[8];
    const void* ada_cw = d_in[9]; const void* ada_cb = d_in[10];
    const void* wq = d_in[11]; const void* bq = d_in[12];
    const void* wk = d_in[13]; const void* bk = d_in[14];
    const void* wv = d_in[15]; const void* bv = d_in[16];
    const void* waq = d_in[17]; const void* baq = d_in[18];
    const void* wak = d_in[19]; const void* bak = d_in[20];
    const void* wav = d_in[21]; const void* bav = d_in[22];
    const void* nq_w = d_in[23];
    const void* nk_w = d_in[24];
    const void* naq_w = d_in[25];
    const void* nak_w = d_in[26];
    const void* wo = d_in[27]; const void* bo = d_in[28];
    const void* wao = d_in[29]; const void* bao = d_in[30];
    const void* ffw1 = d_in[31]; const void* ffb1 = d_in[32];
    const void* ffw2 = d_in[33]; const void* ffb2 = d_in[34];
    const void* fcw1 = d_in[35]; const void* fcb1 = d_in[36];
    const void* fcw2 = d_in[37]; const void* fcb2 = d_in[38];

    char* ws = (char*)d_ws;
    size_t off = 0;
    auto alloc = [&](size_t bytes) {
        char* p = ws + off;
        off = (off + bytes + 255) & ~(size_t)255;
        return p;
    };
    int*   FLAG = (int*)alloc(256);
    float* SACT = (float*)alloc(3 * 1536 * 4);
    float* E6   = (float*)alloc((size_t)3 * SIX * 4);
    float* EC   = (float*)alloc((size_t)3 * SIX * 4);
    bf16* NH  = (bf16*)alloc((size_t)TOTAL * DIM * 2);
    bf16* NE  = (bf16*)alloc((size_t)ENCR * DIM * 2);
    bf16* Qb  = (bf16*)alloc((size_t)TOTAL * DIM * 2);
    bf16* Kb  = (bf16*)alloc((size_t)TOTAL * DIM * 2);
    bf16* Vb  = (bf16*)alloc((size_t)TOTAL * DIM * 2);
    bf16* EQb = (bf16*)alloc((size_t)ENCR * DIM * 2);
    bf16* EKb = (bf16*)alloc((size_t)ENCR * DIM * 2);
    bf16* EVb = (bf16*)alloc((size_t)ENCR * DIM * 2);
    bf16* FF1  = (bf16*)alloc((size_t)TOTAL * INNER * 2);
    bf16* FFC1 = (bf16*)alloc((size_t)ENCR * INNER * 2);

    // 0. dtype probe
    probe_kernel<<<1, 256, 0, stream>>>((const unsigned short*)ada_w, FLAG);

    // 1. AdaLN tables
    silu_kernel<<<18, 256, 0, stream>>>(temb, SACT, FLAG);
    ada_kernel<<<144, 256, 0, stream>>>(SACT, ada_w, ada_b, E6, FLAG);
    ada_kernel<<<144, 256, 0, stream>>>(SACT, ada_cw, ada_cb, EC, FLAG);

    // 2. LN + modulate (msa)
    ln_mod_kernel<<<TOTAL, 256, 0, stream>>>(hid, E6, NH, 0, 1, 0, 1, FLAG);
    ln_mod_kernel<<<ENCR, 256, 0, stream>>>(enc, EC, NE, 0, 1, 1, 1, FLAG);

    // 3. QKV projections
    dim3 gh(12, 24), ge(12, 3);
    gemm_kernel<<<gh, 256, 0, stream>>>((const short*)NH, wq, bq, Qb, TOTAL, DIM, DIM, 0, FLAG);
    gemm_kernel<<<gh, 256, 0, stream>>>((const short*)NH, wk, bk, Kb, TOTAL, DIM, DIM, 0, FLAG);
    gemm_kernel<<<gh, 256, 0, stream>>>((const short*)NH, wv, bv, Vb, TOTAL, DIM, DIM, 0, FLAG);
    gemm_kernel<<<ge, 256, 0, stream>>>((const short*)NE, waq, baq, EQb, ENCR, DIM, DIM, 0, FLAG);
    gemm_kernel<<<ge, 256, 0, stream>>>((const short*)NE, wak, bak, EKb, ENCR, DIM, DIM, 0, FLAG);
    gemm_kernel<<<ge, 256, 0, stream>>>((const short*)NE, wav, bav, EVb, ENCR, DIM, DIM, 0, FLAG);

    // 4. per-head RMSNorm on q/k, then RoPE
    rms_kernel<<<(TOTAL * HEADS) / 4, 256, 0, stream>>>(Qb, nq_w, FLAG);
    rms_kernel<<<(TOTAL * HEADS) / 4, 256, 0, stream>>>(Kb, nk_w, FLAG);
    rms_kernel<<<(ENCR * HEADS) / 4, 256, 0, stream>>>(EQb, naq_w, FLAG);
    rms_kernel<<<(ENCR * HEADS) / 4, 256, 0, stream>>>(EKb, nak_w, FLAG);
    rope_kernel<<<(TOTAL * HEADS * 32) / 256, 256, 0, stream>>>(Qb, rope0, rope1, rope2, 0, FLAG);
    rope_kernel<<<(TOTAL * HEADS * 32) / 256, 256, 0, stream>>>(Kb, rope0, rope1, rope2, 0, FLAG);
    rope_kernel<<<(ENCR * HEADS * 32) / 256, 256, 0, stream>>>(EQb, rope0, rope1, rope2, 1, FLAG);
    rope_kernel<<<(ENCR * HEADS * 32) / 256, 256, 0, stream>>>(EKb, rope0, rope1, rope2, 1, FLAG);

    // 5. joint masked attention (writes ATT_H->NH, ATT_E->NE)
    attn_kernel<<<20736, 256, 0, stream>>>(Qb, Kb, Vb, EQb, EKb, EVb, encv, NH, NE);

    // 6. output projections (PROJ_H->Qb, PROJ_E->EQb)
    gemm_kernel<<<gh, 256, 0, stream>>>((const short*)NH, wo, bo, Qb, TOTAL, DIM, DIM, 0, FLAG);
    gemm_kernel<<<ge, 256, 0, stream>>>((const short*)NE, wao, bao, EQb, ENCR, DIM, DIM, 0, FLAG);

    // 7. gated residual #1 (H1->Kb, E1->EKb); base is an input (dual), out is ws
    resid_kernel<<<(TOTAL * DIM) / 256, 256, 0, stream>>>(hid, Qb, E6, 2, 0, Kb, 0, 1, 0, FLAG);
    resid_kernel<<<(ENCR * DIM) / 256, 256, 0, stream>>>(enc, EQb, EC, 2, 1, EKb, 0, 1, 0, FLAG);

    // 8. LN + modulate (mlp) on ws buffers (no dual)
    ln_mod_kernel<<<TOTAL, 256, 0, stream>>>(Kb, E6, Vb, 3, 4, 0, 0, FLAG);
    ln_mod_kernel<<<ENCR, 256, 0, stream>>>(EKb, EC, EVb, 3, 4, 1, 0, FLAG);

    // 9. FFN
    dim3 gf1(48, 24), gf1e(48, 3);
    gemm_kernel<<<gf1, 256, 0, stream>>>((const short*)Vb, ffw1, ffb1, FF1, TOTAL, INNER, DIM, 1, FLAG);
    gemm_kernel<<<gf1e, 256, 0, stream>>>((const short*)EVb, fcw1, fcb1, FFC1, ENCR, INNER, DIM, 1, FLAG);
    gemm_kernel<<<gh, 256, 0, stream>>>((const short*)FF1, ffw2, ffb2, NH, TOTAL, DIM, INNER, 0, FLAG);
    gemm_kernel<<<ge, 256, 0, stream>>>((const short*)FFC1, fcw2, fcb2, NE, ENCR, DIM, INNER, 0, FLAG);

    // 10. gated residual #2 -> outputs (e first, then h), dtype follows flag
    resid_kernel<<<(ENCR * DIM) / 256, 256, 0, stream>>>(EKb, NE, EC, 5, 1, d_out, 0, 0, 1, FLAG);
    resid_kernel<<<(TOTAL * DIM) / 256, 256, 0, stream>>>(Kb, NH, E6, 5, 0, d_out,
                                                          (size_t)ENCR * DIM, 0, 1, FLAG);
}

// Round 3
// 3017.180 us; speedup vs baseline: 2.9186x; 2.9186x over previous
//
#include <hip/hip_runtime.h>
#include <hip/hip_bf16.h>

typedef __hip_bfloat16 bf16;
typedef short s16x8 __attribute__((ext_vector_type(8)));
typedef float f32x4 __attribute__((ext_vector_type(4)));

#define DIM   1536
#define HEADS 24
#define HD    64
#define TOTAL 3072
#define ENCR  384
#define INNER 6144
#define SIX   9216

// ---- dtype-agnostic loads: flag==1 -> inputs are float32, flag==0 -> bf16
__device__ __forceinline__ float ldf(const void* p, size_t i, int f) {
    return f ? ((const float*)p)[i]
             : __bfloat162float(((const bf16*)p)[i]);
}
__device__ __forceinline__ short f2s(float v) {
    bf16 b = __float2bfloat16(v);
    short s; __builtin_memcpy(&s, &b, 2); return s;
}
__device__ __forceinline__ s16x8 ldb8(const void* B, size_t i, int f) {
    s16x8 r;
    if (f) {
        const float4* p = (const float4*)((const float*)B + i);
        float4 x = p[0], y = p[1];
        r[0]=f2s(x.x); r[1]=f2s(x.y); r[2]=f2s(x.z); r[3]=f2s(x.w);
        r[4]=f2s(y.x); r[5]=f2s(y.y); r[6]=f2s(y.z); r[7]=f2s(y.w);
    } else {
        r = *(const s16x8*)((const short*)B + i);
    }
    return r;
}

// ---------------- probe: detect input dtype (bf16 vs f32-as-shorts)
__global__ __launch_bounds__(256) void probe_kernel(const unsigned short* __restrict__ w,
                                                    int* __restrict__ flag) {
    __shared__ int cnt;
    if (threadIdx.x == 0) cnt = 0;
    __syncthreads();
    int local = 0;
    for (int i = threadIdx.x; i < 65536; i += 256) {
        unsigned short u = w[i];
        if (((u >> 7) & 0xFF) == 0xFF) local++;
    }
    atomicAdd(&cnt, local);
    __syncthreads();
    if (threadIdx.x == 0) flag[0] = (cnt > 0) ? 1 : 0;
}

// ---------------------------------------------------------------- silu(temb)
__global__ __launch_bounds__(256) void silu_kernel(const void* __restrict__ temb,
                                                   float* __restrict__ sact,
                                                   const int* __restrict__ flag) {
    int f = flag[0];
    int i = blockIdx.x * 256 + threadIdx.x;
    float x = ldf(temb, i, f);
    sact[i] = x / (1.f + __expf(-x));
}

// -------------------------------------------- e6 = silu(temb) @ W + b (3x9216)
__global__ __launch_bounds__(256) void ada_kernel(const float* __restrict__ sact,
                                                  const void* __restrict__ W,
                                                  const void* __restrict__ bias,
                                                  float* __restrict__ out,
                                                  const int* __restrict__ flag) {
    int f = flag[0];
    __shared__ float red[3][4][64];
    int c   = threadIdx.x & 63;
    int col = blockIdx.x * 64 + c;
    int kq  = threadIdx.x >> 6;
    float a0 = 0.f, a1 = 0.f, a2 = 0.f;
    for (int k = kq * 384; k < kq * 384 + 384; ++k) {
        float wv = ldf(W, (size_t)k * SIX + col, f);
        a0 += sact[k] * wv;
        a1 += sact[1536 + k] * wv;
        a2 += sact[3072 + k] * wv;
    }
    red[0][kq][c] = a0; red[1][kq][c] = a1; red[2][kq][c] = a2;
    __syncthreads();
    if (kq < 3) {
        float s = red[kq][0][c] + red[kq][1][c] + red[kq][2][c] + red[kq][3][c]
                + ldf(bias, col, f);
        out[(size_t)kq * SIX + col] = s;
    }
}

// ------------------------- LayerNorm + AdaLN modulate
__global__ __launch_bounds__(256) void ln_mod_kernel(const void* __restrict__ x,
                                                     const float* __restrict__ ada,
                                                     bf16* __restrict__ out,
                                                     int shift_sel, int scale_sel,
                                                     int is_enc, int x_dual,
                                                     const int* __restrict__ flag) {
    int f = x_dual ? flag[0] : 0;
    __shared__ float r1[256], r2[256];
    int t = blockIdx.x, tid = threadIdx.x;
    int stage = is_enc ? (t >> 7) : (t < 512 ? 0 : (t < 1536 ? 1 : 2));
    float v[6]; float s = 0.f, s2 = 0.f;
#pragma unroll
    for (int i = 0; i < 6; ++i) {
        float a = ldf(x, (size_t)t * DIM + tid + i * 256, f);
        v[i] = a; s += a; s2 += a * a;
    }
    r1[tid] = s; r2[tid] = s2;
    __syncthreads();
    for (int st = 128; st; st >>= 1) {
        if (tid < st) { r1[tid] += r1[tid + st]; r2[tid] += r2[tid + st]; }
        __syncthreads();
    }
    float mean = r1[0] * (1.f / 1536.f);
    float var  = fmaxf(r2[0] * (1.f / 1536.f) - mean * mean, 0.f);
    float inv  = rsqrtf(var + 1e-6f);
    const float* ab = ada + (size_t)stage * SIX;
#pragma unroll
    for (int i = 0; i < 6; ++i) {
        int c = tid + i * 256;
        float sc = ab[scale_sel * DIM + c];
        float sh = ab[shift_sel * DIM + c];
        out[(size_t)t * DIM + c] = __float2bfloat16((v[i] - mean) * inv * (1.f + sc) + sh);
    }
}

// ---------------------------------------------------------------- MFMA GEMM
#define LDK 48
__global__ __launch_bounds__(256) void gemm_kernel(const short* __restrict__ A,
                                                   const void* __restrict__ B,
                                                   const void* __restrict__ bias,
                                                   bf16* __restrict__ C,
                                                   int M, int N, int K, int act,
                                                   const int* __restrict__ flag) {
    int f = flag[0];
    __shared__ __align__(16) short As[128 * LDK];
    __shared__ __align__(16) short Bs[128 * LDK];
    int tid = threadIdx.x;
    int lane = tid & 63, wid = tid >> 6;
    int wy = wid >> 1, wx = wid & 1;
    int m16 = lane & 15, quad = lane >> 4;
    int m0 = blockIdx.y * 128, n0 = blockIdx.x * 128;

    int ar0 = tid >> 2;
    int ac  = (tid & 3) * 8;
    int br0 = tid >> 4;
    int bc  = (tid & 15) * 8;

    f32x4 acc[4][4] = {};

    for (int k0 = 0; k0 < K; k0 += 32) {
        s16x8 a0 = *(const s16x8*)(A + (size_t)(m0 + ar0) * K + k0 + ac);
        s16x8 a1 = *(const s16x8*)(A + (size_t)(m0 + ar0 + 64) * K + k0 + ac);
        s16x8 b0 = ldb8(B, (size_t)(k0 + br0) * N + n0 + bc, f);
        s16x8 b1 = ldb8(B, (size_t)(k0 + br0 + 16) * N + n0 + bc, f);
        __syncthreads();
        *(s16x8*)(&As[ar0 * LDK + ac]) = a0;
        *(s16x8*)(&As[(ar0 + 64) * LDK + ac]) = a1;
#pragma unroll
        for (int i = 0; i < 8; ++i) {
            Bs[(bc + i) * LDK + br0] = b0[i];
            Bs[(bc + i) * LDK + br0 + 16] = b1[i];
        }
        __syncthreads();
        s16x8 af[4], bfr[4];
#pragma unroll
        for (int i = 0; i < 4; ++i) {
            af[i]  = *(const s16x8*)(&As[(wy * 64 + i * 16 + m16) * LDK + quad * 8]);
            bfr[i] = *(const s16x8*)(&Bs[(wx * 64 + i * 16 + m16) * LDK + quad * 8]);
        }
#pragma unroll
        for (int im = 0; im < 4; ++im)
#pragma unroll
            for (int in = 0; in < 4; ++in)
                acc[im][in] = __builtin_amdgcn_mfma_f32_16x16x32_bf16(
                    af[im], bfr[in], acc[im][in], 0, 0, 0);
    }

#pragma unroll
    for (int in = 0; in < 4; ++in) {
        int gn = n0 + wx * 64 + in * 16 + m16;
        float bsv = ldf(bias, gn, f);
#pragma unroll
        for (int im = 0; im < 4; ++im) {
#pragma unroll
            for (int r = 0; r < 4; ++r) {
                int gm = m0 + wy * 64 + im * 16 + quad * 4 + r;
                float v = acc[im][in][r] + bsv;
                if (act == 1) {
                    float xx = v;
                    v = 0.5f * xx * (1.f + tanhf(0.7978845608028654f *
                                                 (xx + 0.044715f * xx * xx * xx)));
                }
                C[(size_t)gm * N + gn] = __float2bfloat16(v);
            }
        }
    }
}

// -------------------------------------- per-(token,head) RMSNorm over 64, in-place
__global__ __launch_bounds__(256) void rms_kernel(bf16* __restrict__ x,
                                                  const void* __restrict__ w,
                                                  const int* __restrict__ flag) {
    int f = flag[0];
    int g = blockIdx.x * 4 + (threadIdx.x >> 6);
    int lane = threadIdx.x & 63;
    float v = __bfloat162float(x[(size_t)g * 64 + lane]);
    float ss = v * v;
#pragma unroll
    for (int off = 32; off; off >>= 1) ss += __shfl_xor(ss, off);
    float inv = rsqrtf(ss * (1.f / 64.f) + 1e-6f);
    x[(size_t)g * 64 + lane] = __float2bfloat16(v * inv * ldf(w, lane, f));
}

// ----------------------------------------------------- rotation-matrix RoPE in-place
__global__ __launch_bounds__(256) void rope_kernel(bf16* __restrict__ x,
                                                   const void* __restrict__ r0,
                                                   const void* __restrict__ r1,
                                                   const void* __restrict__ r2,
                                                   int is_enc,
                                                   const int* __restrict__ flag) {
    int f = flag[0];
    int gid = blockIdx.x * 256 + threadIdx.x;
    int d2 = gid & 31;
    int th = gid >> 5;
    int h = th % 24;
    int t = th / 24;
    int stage, pos;
    if (is_enc) { stage = t >> 7; pos = t & 127; }
    else if (t < 512)  { stage = 0; pos = 128 + t; }
    else if (t < 1536) { stage = 1; pos = 128 + t - 512; }
    else               { stage = 2; pos = 128 + t - 1536; }
    const void* rt = stage == 0 ? r0 : (stage == 1 ? r1 : r2);
    size_t ro = ((size_t)pos * 32 + d2) * 4;
    float c00 = ldf(rt, ro + 0, f);
    float c01 = ldf(rt, ro + 1, f);
    float c10 = ldf(rt, ro + 2, f);
    float c11 = ldf(rt, ro + 3, f);
    size_t i0 = ((size_t)t * 24 + h) * 64 + d2 * 2;
    float x0 = __bfloat162float(x[i0]), x1 = __bfloat162float(x[i0 + 1]);
    x[i0]     = __float2bfloat16(c00 * x0 + c01 * x1);
    x[i0 + 1] = __float2bfloat16(c10 * x0 + c11 * x1);
}

// ------------------------------------- build VJt[h][d][token] per stage (for PV)
// VJt row layout: stage offsets 0 / 24*64*640 / 24*64*(640+1152); within a stage,
// row (h*64+d) has S contiguous tokens (enc 128 first, then hidden).
__global__ __launch_bounds__(256) void vjt_kernel(const bf16* __restrict__ Vb,
                                                  const bf16* __restrict__ EVb,
                                                  bf16* __restrict__ VJt) {
    __shared__ short T[64][72];
    int b = blockIdx.x;          // 54 j-tiles * 24 heads
    int h = b % 24, jt = b / 24;
    int s, j0, S, hbase; size_t off;
    if (jt < 10)      { s = 0; j0 = jt * 64;        S = 640;  hbase = 0;    off = 0; }
    else if (jt < 28) { s = 1; j0 = (jt - 10) * 64; S = 1152; hbase = 512;  off = (size_t)24 * 64 * 640; }
    else              { s = 2; j0 = (jt - 28) * 64; S = 1664; hbase = 1536; off = (size_t)24 * 64 * (640 + 1152); }
    int tid = threadIdx.x;
    int tr = tid >> 2, tc = (tid & 3) * 16;
    int j = j0 + tr;
    const bf16* vr = (j < 128) ? EVb + ((size_t)(s * 128 + j) * DIM + h * HD)
                               : Vb + ((size_t)(hbase + j - 128) * DIM + h * HD);
    *(s16x8*)&T[tr][tc]     = *(const s16x8*)((const short*)vr + tc);
    *(s16x8*)&T[tr][tc + 8] = *(const s16x8*)((const short*)vr + tc + 8);
    __syncthreads();
    int d = tid >> 2, c0 = (tid & 3) * 16;
    s16x8 o0, o1;
#pragma unroll
    for (int i = 0; i < 8; ++i) o0[i] = T[c0 + i][d];
#pragma unroll
    for (int i = 0; i < 8; ++i) o1[i] = T[c0 + 8 + i][d];
    short* orow = (short*)VJt + off + (size_t)(h * HD + d) * S + j0 + c0;
    *(s16x8*)orow = o0;
    *(s16x8*)(orow + 8) = o1;
}

// -------------------------------------------------- MFMA tiled flash attention
// block = 4 waves = 64-query tile of one (stage, head); wave = 16 queries.
// K-loop in 32-key tiles: S=Q·K^T (4 mfma) -> online softmax -> P·V (4 mfma).
__global__ __launch_bounds__(256) void attn_mfma_kernel(const bf16* __restrict__ Qb,
                                                        const bf16* __restrict__ Kb,
                                                        const bf16* __restrict__ EQ,
                                                        const bf16* __restrict__ EK,
                                                        const bf16* __restrict__ VJt,
                                                        const int* __restrict__ encv,
                                                        bf16* __restrict__ AH,
                                                        bf16* __restrict__ AE) {
    __shared__ __align__(16) short Ks[32 * 72];
    __shared__ __align__(16) short Vt[64 * 40];
    __shared__ __align__(16) short Ps[4][16 * 40];
    int tid = threadIdx.x, wid = tid >> 6, lane = tid & 63;
    int lane15 = lane & 15, quad = lane >> 4;
    int b = blockIdx.x;
    int h = b % 24, qt = b / 24;
    int s, qt0, S, hbase; size_t voff;
    if (qt < 10)      { s = 0; qt0 = qt;      S = 640;  hbase = 0;    voff = 0; }
    else if (qt < 28) { s = 1; qt0 = qt - 10; S = 1152; hbase = 512;  voff = (size_t)24 * 64 * 640; }
    else              { s = 2; qt0 = qt - 28; S = 1664; hbase = 1536; voff = (size_t)24 * 64 * (640 + 1152); }
    const short* vbase = (const short*)VJt + voff + (size_t)h * HD * S;
    int ev = encv[s];
    int qbase = qt0 * 64 + wid * 16;

    // Q fragments, scaled by exactly 2^-3 (exponent-only => exact in bf16)
    int q = qbase + lane15;
    const short* qrow = (q < 128)
        ? (const short*)EQ + ((size_t)(s * 128 + q) * DIM + h * HD)
        : (const short*)Qb + ((size_t)(hbase + q - 128) * DIM + h * HD);
    s16x8 qa[2];
#pragma unroll
    for (int k0 = 0; k0 < 2; ++k0) {
        s16x8 x = *(const s16x8*)(qrow + k0 * 32 + quad * 8);
#pragma unroll
        for (int i = 0; i < 8; ++i) {
            union { unsigned int u; float fl; } t;
            t.u = ((unsigned int)(unsigned short)x[i]) << 16;
            t.fl *= 0.125f;
            x[i] = (short)(t.u >> 16);
        }
        qa[k0] = x;
    }

    f32x4 o[4] = {};
    float mrun[4] = {-1e30f, -1e30f, -1e30f, -1e30f};
    float lrun[4] = {};

    int nkb = S >> 5;
    for (int kb = 0; kb < nkb; ++kb) {
        __syncthreads();
        // stage K tile [32 keys][64 d], rows padded to 72 shorts
        {
            int kr = tid >> 3, kc = (tid & 7) * 8;
            int kg = kb * 32 + kr;
            const short* krow = (kg < 128)
                ? (const short*)EK + ((size_t)(s * 128 + kg) * DIM + h * HD)
                : (const short*)Kb + ((size_t)(hbase + kg - 128) * DIM + h * HD);
            *(s16x8*)&Ks[kr * 72 + kc] = *(const s16x8*)(krow + kc);
        }
        // stage V tile transposed [64 d][32 keys], rows padded to 40 shorts
        {
            int vd = tid >> 2, vc = (tid & 3) * 8;
            *(s16x8*)&Vt[vd * 40 + vc] =
                *(const s16x8*)(vbase + (size_t)vd * S + kb * 32 + vc);
        }
        __syncthreads();

        // S = Q K^T  (two 16-key column groups)
        f32x4 sacc[2];
#pragma unroll
        for (int g = 0; g < 2; ++g) {
            s16x8 kf0 = *(const s16x8*)&Ks[(g * 16 + lane15) * 72 + quad * 8];
            s16x8 kf1 = *(const s16x8*)&Ks[(g * 16 + lane15) * 72 + 32 + quad * 8];
            f32x4 c = {};
            c = __builtin_amdgcn_mfma_f32_16x16x32_bf16(qa[0], kf0, c, 0, 0, 0);
            c = __builtin_amdgcn_mfma_f32_16x16x32_bf16(qa[1], kf1, c, 0, 0, 0);
            int keyg = kb * 32 + g * 16 + lane15;
            if (keyg >= ev && keyg < 128) {
#pragma unroll
                for (int r = 0; r < 4; ++r) c[r] = -1e30f;
            }
            sacc[g] = c;
        }
        // online softmax over rows (row = quad*4 + r; reduce over 16 lanes)
        float mt[4], al[4], ps[4];
#pragma unroll
        for (int r = 0; r < 4; ++r) mt[r] = fmaxf(sacc[0][r], sacc[1][r]);
#pragma unroll
        for (int off = 1; off < 16; off <<= 1)
#pragma unroll
            for (int r = 0; r < 4; ++r) mt[r] = fmaxf(mt[r], __shfl_xor(mt[r], off));
#pragma unroll
        for (int r = 0; r < 4; ++r) {
            float mn = fmaxf(mrun[r], mt[r]);
            al[r] = __expf(mrun[r] - mn);
            mrun[r] = mn;
        }
#pragma unroll
        for (int g = 0; g < 2; ++g)
#pragma unroll
            for (int r = 0; r < 4; ++r)
                sacc[g][r] = __expf(sacc[g][r] - mrun[r]);
#pragma unroll
        for (int r = 0; r < 4; ++r) ps[r] = sacc[0][r] + sacc[1][r];
#pragma unroll
        for (int off = 1; off < 16; off <<= 1)
#pragma unroll
            for (int r = 0; r < 4; ++r) ps[r] += __shfl_xor(ps[r], off);
#pragma unroll
        for (int r = 0; r < 4; ++r) lrun[r] = lrun[r] * al[r] + ps[r];
#pragma unroll
        for (int dc = 0; dc < 4; ++dc)
#pragma unroll
            for (int r = 0; r < 4; ++r) o[dc][r] *= al[r];
        // P: C-layout -> A-layout via per-wave LDS
#pragma unroll
        for (int g = 0; g < 2; ++g)
#pragma unroll
            for (int r = 0; r < 4; ++r)
                Ps[wid][(quad * 4 + r) * 40 + g * 16 + lane15] = f2s(sacc[g][r]);
        s16x8 pa = *(const s16x8*)&Ps[wid][lane15 * 40 + quad * 8];
        // O += P V
#pragma unroll
        for (int dc = 0; dc < 4; ++dc) {
            s16x8 vf = *(const s16x8*)&Vt[(dc * 16 + lane15) * 40 + quad * 8];
            o[dc] = __builtin_amdgcn_mfma_f32_16x16x32_bf16(pa, vf, o[dc], 0, 0, 0);
        }
    }

    float invl[4];
#pragma unroll
    for (int r = 0; r < 4; ++r) invl[r] = 1.f / fmaxf(lrun[r], 1e-37f);
#pragma unroll
    for (int r = 0; r < 4; ++r) {
        int qr = qbase + quad * 4 + r;
        bf16* orow = (qr < 128)
            ? AE + ((size_t)(s * 128 + qr) * DIM + h * HD)
            : AH + ((size_t)(hbase + qr - 128) * DIM + h * HD);
#pragma unroll
        for (int dc = 0; dc < 4; ++dc)
            orow[dc * 16 + lane15] = __float2bfloat16(o[dc][r] * invl[r]);
    }
}

// --------------------- out = base + gate[stage]*delta
__global__ __launch_bounds__(256) void resid_kernel(const void* __restrict__ base,
                                                    const bf16* __restrict__ delta,
                                                    const float* __restrict__ ada,
                                                    int gate_sel, int is_enc,
                                                    void* __restrict__ out,
                                                    size_t out_off,
                                                    int base_dual, int out_dual,
                                                    const int* __restrict__ flag) {
    int bfl = base_dual ? flag[0] : 0;
    int ofl = out_dual ? flag[0] : 0;
    int gid = blockIdx.x * 256 + threadIdx.x;
    int t = gid / DIM, c = gid - t * DIM;
    int stage = is_enc ? (t >> 7) : (t < 512 ? 0 : (t < 1536 ? 1 : 2));
    float g = ada[(size_t)stage * SIX + gate_sel * DIM + c];
    float v = ldf(base, gid, bfl) + g * __bfloat162float(delta[gid]);
    if (ofl) ((float*)out)[out_off + gid] = v;
    else     ((bf16*)out)[out_off + gid] = __float2bfloat16(v);
}

extern "C" void kernel_launch(void* const* d_in, const int* in_sizes, int n_in,
                              void* d_out, int out_size, void* d_ws, size_t ws_size,
                              hipStream_t stream) {
    (void)in_sizes; (void)n_in; (void)out_size; (void)ws_size;
    const void* hid   = d_in[0];
    const void* enc   = d_in[1];
    const void* temb  = d_in[2];
    const int*  encv  = (const int*)d_in[3];
    const void* rope0 = d_in[4];
    const void* rope1 = d_in[5];
    const void* rope2 = d_in[6];
    const void* ada_w = d_in[7];  const void* ada_b = d_in[8];
    const void* ada_cw = d_in[9]; const void* ada_cb = d_in[10];
    const void* wq = d_in[11]; const void* bq = d_in[12];
    const void* wk = d_in[13]; const void* bk = d_in[14];
    const void* wv = d_in[15]; const void* bv = d_in[16];
    const void* waq = d_in[17]; const void* baq = d_in[18];
    const void* wak = d_in[19]; const void* bak = d_in[20];
    const void* wav = d_in[21]; const void* bav = d_in[22];
    const void* nq_w = d_in[23];
    const void* nk_w = d_in[24];
    const void* naq_w = d_in[25];
    const void* nak_w = d_in[26];
    const void* wo = d_in[27]; const void* bo = d_in[28];
    const void* wao = d_in[29]; const void* bao = d_in[30];
    const void* ffw1 = d_in[31]; const void* ffb1 = d_in[32];
    const void* ffw2 = d_in[33]; const void* ffb2 = d_in[34];
    const void* fcw1 = d_in[35]; const void* fcb1 = d_in[36];
    const void* fcw2 = d_in[37]; const void* fcb2 = d_in[38];

    char* ws = (char*)d_ws;
    size_t off = 0;
    auto alloc = [&](size_t bytes) {
        char* p = ws + off;
        off = (off + bytes + 255) & ~(size_t)255;
        return p;
    };
    int*   FLAG = (int*)alloc(256);
    float* SACT = (float*)alloc(3 * 1536 * 4);
    float* E6   = (float*)alloc((size_t)3 * SIX * 4);
    float* EC   = (float*)alloc((size_t)3 * SIX * 4);
    bf16* NH  = (bf16*)alloc((size_t)TOTAL * DIM * 2);
    bf16* NE  = (bf16*)alloc((size_t)ENCR * DIM * 2);
    bf16* Qb  = (bf16*)alloc((size_t)TOTAL * DIM * 2);
    bf16* Kb  = (bf16*)alloc((size_t)TOTAL * DIM * 2);
    bf16* Vb  = (bf16*)alloc((size_t)TOTAL * DIM * 2);
    bf16* EQb = (bf16*)alloc((size_t)ENCR * DIM * 2);
    bf16* EKb = (bf16*)alloc((size_t)ENCR * DIM * 2);
    bf16* EVb = (bf16*)alloc((size_t)ENCR * DIM * 2);
    bf16* VJT = (bf16*)alloc((size_t)24 * 64 * (640 + 1152 + 1664) * 2);
    bf16* FF1  = (bf16*)alloc((size_t)TOTAL * INNER * 2);
    bf16* FFC1 = (bf16*)alloc((size_t)ENCR * INNER * 2);

    // 0. dtype probe
    probe_kernel<<<1, 256, 0, stream>>>((const unsigned short*)ada_w, FLAG);

    // 1. AdaLN tables
    silu_kernel<<<18, 256, 0, stream>>>(temb, SACT, FLAG);
    ada_kernel<<<144, 256, 0, stream>>>(SACT, ada_w, ada_b, E6, FLAG);
    ada_kernel<<<144, 256, 0, stream>>>(SACT, ada_cw, ada_cb, EC, FLAG);

    // 2. LN + modulate (msa)
    ln_mod_kernel<<<TOTAL, 256, 0, stream>>>(hid, E6, NH, 0, 1, 0, 1, FLAG);
    ln_mod_kernel<<<ENCR, 256, 0, stream>>>(enc, EC, NE, 0, 1, 1, 1, FLAG);

    // 3. QKV projections
    dim3 gh(12, 24), ge(12, 3);
    gemm_kernel<<<gh, 256, 0, stream>>>((const short*)NH, wq, bq, Qb, TOTAL, DIM, DIM, 0, FLAG);
    gemm_kernel<<<gh, 256, 0, stream>>>((const short*)NH, wk, bk, Kb, TOTAL, DIM, DIM, 0, FLAG);
    gemm_kernel<<<gh, 256, 0, stream>>>((const short*)NH, wv, bv, Vb, TOTAL, DIM, DIM, 0, FLAG);
    gemm_kernel<<<ge, 256, 0, stream>>>((const short*)NE, waq, baq, EQb, ENCR, DIM, DIM, 0, FLAG);
    gemm_kernel<<<ge, 256, 0, stream>>>((const short*)NE, wak, bak, EKb, ENCR, DIM, DIM, 0, FLAG);
    gemm_kernel<<<ge, 256, 0, stream>>>((const short*)NE, wav, bav, EVb, ENCR, DIM, DIM, 0, FLAG);

    // 4. per-head RMSNorm on q/k, then RoPE
    rms_kernel<<<(TOTAL * HEADS) / 4, 256, 0, stream>>>(Qb, nq_w, FLAG);
    rms_kernel<<<(TOTAL * HEADS) / 4, 256, 0, stream>>>(Kb, nk_w, FLAG);
    rms_kernel<<<(ENCR * HEADS) / 4, 256, 0, stream>>>(EQb, naq_w, FLAG);
    rms_kernel<<<(ENCR * HEADS) / 4, 256, 0, stream>>>(EKb, nak_w, FLAG);
    rope_kernel<<<(TOTAL * HEADS * 32) / 256, 256, 0, stream>>>(Qb, rope0, rope1, rope2, 0, FLAG);
    rope_kernel<<<(TOTAL * HEADS * 32) / 256, 256, 0, stream>>>(Kb, rope0, rope1, rope2, 0, FLAG);
    rope_kernel<<<(ENCR * HEADS * 32) / 256, 256, 0, stream>>>(EQb, rope0, rope1, rope2, 1, FLAG);
    rope_kernel<<<(ENCR * HEADS * 32) / 256, 256, 0, stream>>>(EKb, rope0, rope1, rope2, 1, FLAG);

    // 4b. V joint-transpose for PV B-fragments
    vjt_kernel<<<1296, 256, 0, stream>>>(Vb, EVb, VJT);

    // 5. MFMA flash attention (writes ATT_H->NH, ATT_E->NE)
    attn_mfma_kernel<<<1296, 256, 0, stream>>>(Qb, Kb, EQb, EKb, VJT, encv, NH, NE);

    // 6. output projections (PROJ_H->Qb, PROJ_E->EQb)
    gemm_kernel<<<gh, 256, 0, stream>>>((const short*)NH, wo, bo, Qb, TOTAL, DIM, DIM, 0, FLAG);
    gemm_kernel<<<ge, 256, 0, stream>>>((const short*)NE, wao, bao, EQb, ENCR, DIM, DIM, 0, FLAG);

    // 7. gated residual #1 (H1->Kb, E1->EKb)
    resid_kernel<<<(TOTAL * DIM) / 256, 256, 0, stream>>>(hid, Qb, E6, 2, 0, Kb, 0, 1, 0, FLAG);
    resid_kernel<<<(ENCR * DIM) / 256, 256, 0, stream>>>(enc, EQb, EC, 2, 1, EKb, 0, 1, 0, FLAG);

    // 8. LN + modulate (mlp)
    ln_mod_kernel<<<TOTAL, 256, 0, stream>>>(Kb, E6, Vb, 3, 4, 0, 0, FLAG);
    ln_mod_kernel<<<ENCR, 256, 0, stream>>>(EKb, EC, EVb, 3, 4, 1, 0, FLAG);

    // 9. FFN
    dim3 gf1(48, 24), gf1e(48, 3);
    gemm_kernel<<<gf1, 256, 0, stream>>>((const short*)Vb, ffw1, ffb1, FF1, TOTAL, INNER, DIM, 1, FLAG);
    gemm_kernel<<<gf1e, 256, 0, stream>>>((const short*)EVb, fcw1, fcb1, FFC1, ENCR, INNER, DIM, 1, FLAG);
    gemm_kernel<<<gh, 256, 0, stream>>>((const short*)FF1, ffw2, ffb2, NH, TOTAL, DIM, INNER, 0, FLAG);
    gemm_kernel<<<ge, 256, 0, stream>>>((const short*)FFC1, fcw2, fcb2, NE, ENCR, DIM, INNER, 0, FLAG);

    // 10. gated residual #2 -> outputs (e first, then h)
    resid_kernel<<<(ENCR * DIM) / 256, 256, 0, stream>>>(EKb, NE, EC, 5, 1, d_out, 0, 0, 1, FLAG);
    resid_kernel<<<(TOTAL * DIM) / 256, 256, 0, stream>>>(Kb, NH, E6, 5, 0, d_out,
                                                          (size_t)ENCR * DIM, 0, 1, FLAG);
}

// Round 4
// 1702.352 us; speedup vs baseline: 5.1728x; 1.7724x over previous
//
#include <hip/hip_runtime.h>
#include <hip/hip_bf16.h>

typedef __hip_bfloat16 bf16;
typedef short s16x8 __attribute__((ext_vector_type(8)));
typedef float f32x4 __attribute__((ext_vector_type(4)));

#define DIM   1536
#define HEADS 24
#define HD    64
#define TOTAL 3072
#define ENCR  384
#define INNER 6144
#define SIX   9216

// ---- dtype-agnostic loads: flag==1 -> inputs are float32, flag==0 -> bf16
__device__ __forceinline__ float ldf(const void* p, size_t i, int f) {
    return f ? ((const float*)p)[i]
             : __bfloat162float(((const bf16*)p)[i]);
}
__device__ __forceinline__ short f2s(float v) {
    bf16 b = __float2bfloat16(v);
    short s; __builtin_memcpy(&s, &b, 2); return s;
}
__device__ __forceinline__ s16x8 ldb8(const void* B, size_t i, int f) {
    s16x8 r;
    if (f) {
        const float4* p = (const float4*)((const float*)B + i);
        float4 x = p[0], y = p[1];
        r[0]=f2s(x.x); r[1]=f2s(x.y); r[2]=f2s(x.z); r[3]=f2s(x.w);
        r[4]=f2s(y.x); r[5]=f2s(y.y); r[6]=f2s(y.z); r[7]=f2s(y.w);
    } else {
        r = *(const s16x8*)((const short*)B + i);
    }
    return r;
}
// async global->LDS, 16B per lane; lds base must be wave-uniform
__device__ __forceinline__ void gld16(const void* g, void* l) {
    __builtin_amdgcn_global_load_lds(
        (const __attribute__((address_space(1))) unsigned int*)g,
        (__attribute__((address_space(3))) unsigned int*)l, 16, 0, 0);
}

// ---------------- probe: detect input dtype (bf16 vs f32-as-shorts)
__global__ __launch_bounds__(256) void probe_kernel(const unsigned short* __restrict__ w,
                                                    int* __restrict__ flag) {
    __shared__ int cnt;
    if (threadIdx.x == 0) cnt = 0;
    __syncthreads();
    int local = 0;
    for (int i = threadIdx.x; i < 65536; i += 256) {
        unsigned short u = w[i];
        if (((u >> 7) & 0xFF) == 0xFF) local++;
    }
    atomicAdd(&cnt, local);
    __syncthreads();
    if (threadIdx.x == 0) flag[0] = (cnt > 0) ? 1 : 0;
}

// ---------------------------------------------------------------- silu(temb)
__global__ __launch_bounds__(256) void silu_kernel(const void* __restrict__ temb,
                                                   float* __restrict__ sact,
                                                   const int* __restrict__ flag) {
    int f = flag[0];
    int i = blockIdx.x * 256 + threadIdx.x;
    float x = ldf(temb, i, f);
    sact[i] = x / (1.f + __expf(-x));
}

// -------------------------------------------- e6 = silu(temb) @ W + b (3x9216)
__global__ __launch_bounds__(256) void ada_kernel(const float* __restrict__ sact,
                                                  const void* __restrict__ W,
                                                  const void* __restrict__ bias,
                                                  float* __restrict__ out,
                                                  const int* __restrict__ flag) {
    int f = flag[0];
    __shared__ float red[3][4][64];
    int c   = threadIdx.x & 63;
    int col = blockIdx.x * 64 + c;
    int kq  = threadIdx.x >> 6;
    float a0 = 0.f, a1 = 0.f, a2 = 0.f;
    for (int k = kq * 384; k < kq * 384 + 384; ++k) {
        float wv = ldf(W, (size_t)k * SIX + col, f);
        a0 += sact[k] * wv;
        a1 += sact[1536 + k] * wv;
        a2 += sact[3072 + k] * wv;
    }
    red[0][kq][c] = a0; red[1][kq][c] = a1; red[2][kq][c] = a2;
    __syncthreads();
    if (kq < 3) {
        float s = red[kq][0][c] + red[kq][1][c] + red[kq][2][c] + red[kq][3][c]
                + ldf(bias, col, f);
        out[(size_t)kq * SIX + col] = s;
    }
}

// ------------------------- LayerNorm + AdaLN modulate
__global__ __launch_bounds__(256) void ln_mod_kernel(const void* __restrict__ x,
                                                     const float* __restrict__ ada,
                                                     bf16* __restrict__ out,
                                                     int shift_sel, int scale_sel,
                                                     int is_enc, int x_dual,
                                                     const int* __restrict__ flag) {
    int f = x_dual ? flag[0] : 0;
    __shared__ float r1[256], r2[256];
    int t = blockIdx.x, tid = threadIdx.x;
    int stage = is_enc ? (t >> 7) : (t < 512 ? 0 : (t < 1536 ? 1 : 2));
    float v[6]; float s = 0.f, s2 = 0.f;
#pragma unroll
    for (int i = 0; i < 6; ++i) {
        float a = ldf(x, (size_t)t * DIM + tid + i * 256, f);
        v[i] = a; s += a; s2 += a * a;
    }
    r1[tid] = s; r2[tid] = s2;
    __syncthreads();
    for (int st = 128; st; st >>= 1) {
        if (tid < st) { r1[tid] += r1[tid + st]; r2[tid] += r2[tid + st]; }
        __syncthreads();
    }
    float mean = r1[0] * (1.f / 1536.f);
    float var  = fmaxf(r2[0] * (1.f / 1536.f) - mean * mean, 0.f);
    float inv  = rsqrtf(var + 1e-6f);
    const float* ab = ada + (size_t)stage * SIX;
#pragma unroll
    for (int i = 0; i < 6; ++i) {
        int c = tid + i * 256;
        float sc = ab[scale_sel * DIM + c];
        float sh = ab[shift_sel * DIM + c];
        out[(size_t)t * DIM + c] = __float2bfloat16((v[i] - mean) * inv * (1.f + sc) + sh);
    }
}

// -------------------------- weight transpose: W[K][N] -> WT[N][K] (bf16 out)
// grid (N/64, K/64), block 256
__global__ __launch_bounds__(256) void wt_kernel(const void* __restrict__ W,
                                                 bf16* __restrict__ WT,
                                                 int K, int N,
                                                 const int* __restrict__ flag) {
    int f = flag[0];
    __shared__ short T[64][72];
    int n0 = blockIdx.x * 64, k0 = blockIdx.y * 64;
    int tid = threadIdx.x;
    int r = tid >> 2, c0 = (tid & 3) * 16;
#pragma unroll
    for (int i = 0; i < 16; ++i)
        T[r][c0 + i] = f2s(ldf(W, (size_t)(k0 + r) * N + n0 + c0 + i, f));
    __syncthreads();
    int n = tid >> 2, kc = (tid & 3) * 16;
    s16x8 o0, o1;
#pragma unroll
    for (int i = 0; i < 8; ++i) o0[i] = T[kc + i][n];
#pragma unroll
    for (int i = 0; i < 8; ++i) o1[i] = T[kc + 8 + i][n];
    short* orow = (short*)WT + (size_t)(n0 + n) * K + k0 + kc;
    *(s16x8*)orow = o0;
    *(s16x8*)(orow + 8) = o1;
}

// ------------------------- transposed-B MFMA GEMM (m97-style, async staging)
// C[M, Nout(xn)] = act(A[M,K] @ Bt[N,K]^T + bias).  128x128 tile, BK=32.
// Up to 3 stacked output buffers (fused QKV): sel = n0 / Nout.
// XOR chunk swizzle on the global side of global_load_lds kills LDS read
// conflicts (2 rows per (parity,chunk) slot -> 2-way, free per m136).
__global__ __launch_bounds__(256) void gemm_t_kernel(const short* __restrict__ A,
                                                     const short* __restrict__ Bt,
                                                     const void* __restrict__ B0,
                                                     const void* __restrict__ B1,
                                                     const void* __restrict__ B2,
                                                     bf16* __restrict__ O0,
                                                     bf16* __restrict__ O1,
                                                     bf16* __restrict__ O2,
                                                     int Nout, int K, int act,
                                                     const int* __restrict__ flag) {
    int f = flag[0];
    __shared__ __align__(16) short As[128 * 32];
    __shared__ __align__(16) short Bs[128 * 32];
    int tid = threadIdx.x;
    int lane = tid & 63, wid = tid >> 6;
    int wy = wid >> 1, wx = wid & 1;
    int lane15 = lane & 15, quad = lane >> 4;
    int m0 = blockIdx.y * 128, n0 = blockIdx.x * 128;
    int lr = lane >> 2, lc = lane & 3;

    f32x4 acc[4][4] = {};

    for (int k0 = 0; k0 < K; k0 += 32) {
        __syncthreads();
#pragma unroll
        for (int c = 0; c < 2; ++c) {
            int rb = wid * 32 + c * 16;
            int r = rb + lr;
            int gc = (lc - (r >> 1)) & 3;
            gld16(A + (size_t)(m0 + r) * K + k0 + gc * 8, &As[rb * 32]);
            gld16(Bt + (size_t)(n0 + r) * K + k0 + gc * 8, &Bs[rb * 32]);
        }
        __syncthreads();   // compiler drains vmcnt before s_barrier
        s16x8 af[4], bfr[4];
#pragma unroll
        for (int i = 0; i < 4; ++i) {
            int ra = wy * 64 + i * 16 + lane15;
            af[i] = *(const s16x8*)&As[ra * 32 + ((quad + (ra >> 1)) & 3) * 8];
            int rb2 = wx * 64 + i * 16 + lane15;
            bfr[i] = *(const s16x8*)&Bs[rb2 * 32 + ((quad + (rb2 >> 1)) & 3) * 8];
        }
#pragma unroll
        for (int im = 0; im < 4; ++im)
#pragma unroll
            for (int in = 0; in < 4; ++in)
                acc[im][in] = __builtin_amdgcn_mfma_f32_16x16x32_bf16(
                    af[im], bfr[in], acc[im][in], 0, 0, 0);
    }

    int sel = n0 / Nout;
    int nb = n0 - sel * Nout;
    bf16* Cout = sel == 0 ? O0 : (sel == 1 ? O1 : O2);
    const void* bs = sel == 0 ? B0 : (sel == 1 ? B1 : B2);

#pragma unroll
    for (int in = 0; in < 4; ++in) {
        int gn = nb + wx * 64 + in * 16 + lane15;
        float bsv = ldf(bs, gn, f);
#pragma unroll
        for (int im = 0; im < 4; ++im) {
#pragma unroll
            for (int r = 0; r < 4; ++r) {
                int gm = m0 + wy * 64 + im * 16 + quad * 4 + r;
                float v = acc[im][in][r] + bsv;
                if (act == 1) {
                    float xx = v;
                    v = 0.5f * xx * (1.f + tanhf(0.7978845608028654f *
                                                 (xx + 0.044715f * xx * xx * xx)));
                }
                Cout[(size_t)gm * Nout + gn] = __float2bfloat16(v);
            }
        }
    }
}

// ---------------------------------------------------------------- legacy GEMM
// (fallback when ws is too small for transposed weights)
#define LDK 48
__global__ __launch_bounds__(256) void gemm_kernel(const short* __restrict__ A,
                                                   const void* __restrict__ B,
                                                   const void* __restrict__ bias,
                                                   bf16* __restrict__ C,
                                                   int M, int N, int K, int act,
                                                   const int* __restrict__ flag) {
    int f = flag[0];
    __shared__ __align__(16) short As[128 * LDK];
    __shared__ __align__(16) short Bs[128 * LDK];
    int tid = threadIdx.x;
    int lane = tid & 63, wid = tid >> 6;
    int wy = wid >> 1, wx = wid & 1;
    int m16 = lane & 15, quad = lane >> 4;
    int m0 = blockIdx.y * 128, n0 = blockIdx.x * 128;
    int ar0 = tid >> 2;
    int ac  = (tid & 3) * 8;
    int br0 = tid >> 4;
    int bc  = (tid & 15) * 8;
    f32x4 acc[4][4] = {};
    for (int k0 = 0; k0 < K; k0 += 32) {
        s16x8 a0 = *(const s16x8*)(A + (size_t)(m0 + ar0) * K + k0 + ac);
        s16x8 a1 = *(const s16x8*)(A + (size_t)(m0 + ar0 + 64) * K + k0 + ac);
        s16x8 b0 = ldb8(B, (size_t)(k0 + br0) * N + n0 + bc, f);
        s16x8 b1 = ldb8(B, (size_t)(k0 + br0 + 16) * N + n0 + bc, f);
        __syncthreads();
        *(s16x8*)(&As[ar0 * LDK + ac]) = a0;
        *(s16x8*)(&As[(ar0 + 64) * LDK + ac]) = a1;
#pragma unroll
        for (int i = 0; i < 8; ++i) {
            Bs[(bc + i) * LDK + br0] = b0[i];
            Bs[(bc + i) * LDK + br0 + 16] = b1[i];
        }
        __syncthreads();
        s16x8 af[4], bfr[4];
#pragma unroll
        for (int i = 0; i < 4; ++i) {
            af[i]  = *(const s16x8*)(&As[(wy * 64 + i * 16 + m16) * LDK + quad * 8]);
            bfr[i] = *(const s16x8*)(&Bs[(wx * 64 + i * 16 + m16) * LDK + quad * 8]);
        }
#pragma unroll
        for (int im = 0; im < 4; ++im)
#pragma unroll
            for (int in = 0; in < 4; ++in)
                acc[im][in] = __builtin_amdgcn_mfma_f32_16x16x32_bf16(
                    af[im], bfr[in], acc[im][in], 0, 0, 0);
    }
#pragma unroll
    for (int in = 0; in < 4; ++in) {
        int gn = n0 + wx * 64 + in * 16 + m16;
        float bsv = ldf(bias, gn, f);
#pragma unroll
        for (int im = 0; im < 4; ++im) {
#pragma unroll
            for (int r = 0; r < 4; ++r) {
                int gm = m0 + wy * 64 + im * 16 + quad * 4 + r;
                float v = acc[im][in][r] + bsv;
                if (act == 1) {
                    float xx = v;
                    v = 0.5f * xx * (1.f + tanhf(0.7978845608028654f *
                                                 (xx + 0.044715f * xx * xx * xx)));
                }
                C[(size_t)gm * N + gn] = __float2bfloat16(v);
            }
        }
    }
}

// -------------------------------------- per-(token,head) RMSNorm over 64, in-place
__global__ __launch_bounds__(256) void rms_kernel(bf16* __restrict__ x,
                                                  const void* __restrict__ w,
                                                  const int* __restrict__ flag) {
    int f = flag[0];
    int g = blockIdx.x * 4 + (threadIdx.x >> 6);
    int lane = threadIdx.x & 63;
    float v = __bfloat162float(x[(size_t)g * 64 + lane]);
    float ss = v * v;
#pragma unroll
    for (int off = 32; off; off >>= 1) ss += __shfl_xor(ss, off);
    float inv = rsqrtf(ss * (1.f / 64.f) + 1e-6f);
    x[(size_t)g * 64 + lane] = __float2bfloat16(v * inv * ldf(w, lane, f));
}

// ----------------------------------------------------- rotation-matrix RoPE in-place
__global__ __launch_bounds__(256) void rope_kernel(bf16* __restrict__ x,
                                                   const void* __restrict__ r0,
                                                   const void* __restrict__ r1,
                                                   const void* __restrict__ r2,
                                                   int is_enc,
                                                   const int* __restrict__ flag) {
    int f = flag[0];
    int gid = blockIdx.x * 256 + threadIdx.x;
    int d2 = gid & 31;
    int th = gid >> 5;
    int h = th % 24;
    int t = th / 24;
    int stage, pos;
    if (is_enc) { stage = t >> 7; pos = t & 127; }
    else if (t < 512)  { stage = 0; pos = 128 + t; }
    else if (t < 1536) { stage = 1; pos = 128 + t - 512; }
    else               { stage = 2; pos = 128 + t - 1536; }
    const void* rt = stage == 0 ? r0 : (stage == 1 ? r1 : r2);
    size_t ro = ((size_t)pos * 32 + d2) * 4;
    float c00 = ldf(rt, ro + 0, f);
    float c01 = ldf(rt, ro + 1, f);
    float c10 = ldf(rt, ro + 2, f);
    float c11 = ldf(rt, ro + 3, f);
    size_t i0 = ((size_t)t * 24 + h) * 64 + d2 * 2;
    float x0 = __bfloat162float(x[i0]), x1 = __bfloat162float(x[i0 + 1]);
    x[i0]     = __float2bfloat16(c00 * x0 + c01 * x1);
    x[i0 + 1] = __float2bfloat16(c10 * x0 + c11 * x1);
}

// ------------------------------------- build VJt[h][d][token] per stage (for PV)
__global__ __launch_bounds__(256) void vjt_kernel(const bf16* __restrict__ Vb,
                                                  const bf16* __restrict__ EVb,
                                                  bf16* __restrict__ VJt) {
    __shared__ short T[64][72];
    int b = blockIdx.x;
    int h = b % 24, jt = b / 24;
    int s, j0, S, hbase; size_t off;
    if (jt < 10)      { s = 0; j0 = jt * 64;        S = 640;  hbase = 0;    off = 0; }
    else if (jt < 28) { s = 1; j0 = (jt - 10) * 64; S = 1152; hbase = 512;  off = (size_t)24 * 64 * 640; }
    else              { s = 2; j0 = (jt - 28) * 64; S = 1664; hbase = 1536; off = (size_t)24 * 64 * (640 + 1152); }
    int tid = threadIdx.x;
    int tr = tid >> 2, tc = (tid & 3) * 16;
    int j = j0 + tr;
    const bf16* vr = (j < 128) ? EVb + ((size_t)(s * 128 + j) * DIM + h * HD)
                               : Vb + ((size_t)(hbase + j - 128) * DIM + h * HD);
    *(s16x8*)&T[tr][tc]     = *(const s16x8*)((const short*)vr + tc);
    *(s16x8*)&T[tr][tc + 8] = *(const s16x8*)((const short*)vr + tc + 8);
    __syncthreads();
    int d = tid >> 2, c0 = (tid & 3) * 16;
    s16x8 o0, o1;
#pragma unroll
    for (int i = 0; i < 8; ++i) o0[i] = T[c0 + i][d];
#pragma unroll
    for (int i = 0; i < 8; ++i) o1[i] = T[c0 + 8 + i][d];
    short* orow = (short*)VJt + off + (size_t)(h * HD + d) * S + j0 + c0;
    *(s16x8*)orow = o0;
    *(s16x8*)(orow + 8) = o1;
}

// -------------------------------------------------- MFMA tiled flash attention
__global__ __launch_bounds__(256) void attn_mfma_kernel(const bf16* __restrict__ Qb,
                                                        const bf16* __restrict__ Kb,
                                                        const bf16* __restrict__ EQ,
                                                        const bf16* __restrict__ EK,
                                                        const bf16* __restrict__ VJt,
                                                        const int* __restrict__ encv,
                                                        bf16* __restrict__ AH,
                                                        bf16* __restrict__ AE) {
    __shared__ __align__(16) short Ks[32 * 72];
    __shared__ __align__(16) short Vt[64 * 40];
    __shared__ __align__(16) short Ps[4][16 * 40];
    int tid = threadIdx.x, wid = tid >> 6, lane = tid & 63;
    int lane15 = lane & 15, quad = lane >> 4;
    int b = blockIdx.x;
    int h = b % 24, qt = b / 24;
    int s, qt0, S, hbase; size_t voff;
    if (qt < 10)      { s = 0; qt0 = qt;      S = 640;  hbase = 0;    voff = 0; }
    else if (qt < 28) { s = 1; qt0 = qt - 10; S = 1152; hbase = 512;  voff = (size_t)24 * 64 * 640; }
    else              { s = 2; qt0 = qt - 28; S = 1664; hbase = 1536; voff = (size_t)24 * 64 * (640 + 1152); }
    const short* vbase = (const short*)VJt + voff + (size_t)h * HD * S;
    int ev = encv[s];
    int qbase = qt0 * 64 + wid * 16;

    int q = qbase + lane15;
    const short* qrow = (q < 128)
        ? (const short*)EQ + ((size_t)(s * 128 + q) * DIM + h * HD)
        : (const short*)Qb + ((size_t)(hbase + q - 128) * DIM + h * HD);
    s16x8 qa[2];
#pragma unroll
    for (int k0 = 0; k0 < 2; ++k0) {
        s16x8 x = *(const s16x8*)(qrow + k0 * 32 + quad * 8);
#pragma unroll
        for (int i = 0; i < 8; ++i) {
            union { unsigned int u; float fl; } t;
            t.u = ((unsigned int)(unsigned short)x[i]) << 16;
            t.fl *= 0.125f;
            x[i] = (short)(t.u >> 16);
        }
        qa[k0] = x;
    }

    f32x4 o[4] = {};
    float mrun[4] = {-1e30f, -1e30f, -1e30f, -1e30f};
    float lrun[4] = {};

    int nkb = S >> 5;
    for (int kb = 0; kb < nkb; ++kb) {
        __syncthreads();
        {
            int kr = tid >> 3, kc = (tid & 7) * 8;
            int kg = kb * 32 + kr;
            const short* krow = (kg < 128)
                ? (const short*)EK + ((size_t)(s * 128 + kg) * DIM + h * HD)
                : (const short*)Kb + ((size_t)(hbase + kg - 128) * DIM + h * HD);
            *(s16x8*)&Ks[kr * 72 + kc] = *(const s16x8*)(krow + kc);
        }
        {
            int vd = tid >> 2, vc = (tid & 3) * 8;
            *(s16x8*)&Vt[vd * 40 + vc] =
                *(const s16x8*)(vbase + (size_t)vd * S + kb * 32 + vc);
        }
        __syncthreads();

        f32x4 sacc[2];
#pragma unroll
        for (int g = 0; g < 2; ++g) {
            s16x8 kf0 = *(const s16x8*)&Ks[(g * 16 + lane15) * 72 + quad * 8];
            s16x8 kf1 = *(const s16x8*)&Ks[(g * 16 + lane15) * 72 + 32 + quad * 8];
            f32x4 c = {};
            c = __builtin_amdgcn_mfma_f32_16x16x32_bf16(qa[0], kf0, c, 0, 0, 0);
            c = __builtin_amdgcn_mfma_f32_16x16x32_bf16(qa[1], kf1, c, 0, 0, 0);
            int keyg = kb * 32 + g * 16 + lane15;
            if (keyg >= ev && keyg < 128) {
#pragma unroll
                for (int r = 0; r < 4; ++r) c[r] = -1e30f;
            }
            sacc[g] = c;
        }
        float mt[4], al[4], ps[4];
#pragma unroll
        for (int r = 0; r < 4; ++r) mt[r] = fmaxf(sacc[0][r], sacc[1][r]);
#pragma unroll
        for (int off = 1; off < 16; off <<= 1)
#pragma unroll
            for (int r = 0; r < 4; ++r) mt[r] = fmaxf(mt[r], __shfl_xor(mt[r], off));
#pragma unroll
        for (int r = 0; r < 4; ++r) {
            float mn = fmaxf(mrun[r], mt[r]);
            al[r] = __expf(mrun[r] - mn);
            mrun[r] = mn;
        }
#pragma unroll
        for (int g = 0; g < 2; ++g)
#pragma unroll
            for (int r = 0; r < 4; ++r)
                sacc[g][r] = __expf(sacc[g][r] - mrun[r]);
#pragma unroll
        for (int r = 0; r < 4; ++r) ps[r] = sacc[0][r] + sacc[1][r];
#pragma unroll
        for (int off = 1; off < 16; off <<= 1)
#pragma unroll
            for (int r = 0; r < 4; ++r) ps[r] += __shfl_xor(ps[r], off);
#pragma unroll
        for (int r = 0; r < 4; ++r) lrun[r] = lrun[r] * al[r] + ps[r];
#pragma unroll
        for (int dc = 0; dc < 4; ++dc)
#pragma unroll
            for (int r = 0; r < 4; ++r) o[dc][r] *= al[r];
#pragma unroll
        for (int g = 0; g < 2; ++g)
#pragma unroll
            for (int r = 0; r < 4; ++r)
                Ps[wid][(quad * 4 + r) * 40 + g * 16 + lane15] = f2s(sacc[g][r]);
        s16x8 pa = *(const s16x8*)&Ps[wid][lane15 * 40 + quad * 8];
#pragma unroll
        for (int dc = 0; dc < 4; ++dc) {
            s16x8 vf = *(const s16x8*)&Vt[(dc * 16 + lane15) * 40 + quad * 8];
            o[dc] = __builtin_amdgcn_mfma_f32_16x16x32_bf16(pa, vf, o[dc], 0, 0, 0);
        }
    }

    float invl[4];
#pragma unroll
    for (int r = 0; r < 4; ++r) invl[r] = 1.f / fmaxf(lrun[r], 1e-37f);
#pragma unroll
    for (int r = 0; r < 4; ++r) {
        int qr = qbase + quad * 4 + r;
        bf16* orow = (qr < 128)
            ? AE + ((size_t)(s * 128 + qr) * DIM + h * HD)
            : AH + ((size_t)(hbase + qr - 128) * DIM + h * HD);
#pragma unroll
        for (int dc = 0; dc < 4; ++dc)
            orow[dc * 16 + lane15] = __float2bfloat16(o[dc][r] * invl[r]);
    }
}

// --------------------- out = base + gate[stage]*delta
__global__ __launch_bounds__(256) void resid_kernel(const void* __restrict__ base,
                                                    const bf16* __restrict__ delta,
                                                    const float* __restrict__ ada,
                                                    int gate_sel, int is_enc,
                                                    void* __restrict__ out,
                                                    size_t out_off,
                                                    int base_dual, int out_dual,
                                                    const int* __restrict__ flag) {
    int bfl = base_dual ? flag[0] : 0;
    int ofl = out_dual ? flag[0] : 0;
    int gid = blockIdx.x * 256 + threadIdx.x;
    int t = gid / DIM, c = gid - t * DIM;
    int stage = is_enc ? (t >> 7) : (t < 512 ? 0 : (t < 1536 ? 1 : 2));
    float g = ada[(size_t)stage * SIX + gate_sel * DIM + c];
    float v = ldf(base, gid, bfl) + g * __bfloat162float(delta[gid]);
    if (ofl) ((float*)out)[out_off + gid] = v;
    else     ((bf16*)out)[out_off + gid] = __float2bfloat16(v);
}

extern "C" void kernel_launch(void* const* d_in, const int* in_sizes, int n_in,
                              void* d_out, int out_size, void* d_ws, size_t ws_size,
                              hipStream_t stream) {
    (void)in_sizes; (void)n_in; (void)out_size;
    const void* hid   = d_in[0];
    const void* enc   = d_in[1];
    const void* temb  = d_in[2];
    const int*  encv  = (const int*)d_in[3];
    const void* rope0 = d_in[4];
    const void* rope1 = d_in[5];
    const void* rope2 = d_in[6];
    const void* ada_w = d_in[7];  const void* ada_b = d_in[8];
    const void* ada_cw = d_in[9]; const void* ada_cb = d_in[10];
    const void* wq = d_in[11]; const void* bq = d_in[12];
    const void* wk = d_in[13]; const void* bk = d_in[14];
    const void* wv = d_in[15]; const void* bv = d_in[16];
    const void* waq = d_in[17]; const void* baq = d_in[18];
    const void* wak = d_in[19]; const void* bak = d_in[20];
    const void* wav = d_in[21]; const void* bav = d_in[22];
    const void* nq_w = d_in[23];
    const void* nk_w = d_in[24];
    const void* naq_w = d_in[25];
    const void* nak_w = d_in[26];
    const void* wo = d_in[27]; const void* bo = d_in[28];
    const void* wao = d_in[29]; const void* bao = d_in[30];
    const void* ffw1 = d_in[31]; const void* ffb1 = d_in[32];
    const void* ffw2 = d_in[33]; const void* ffb2 = d_in[34];
    const void* fcw1 = d_in[35]; const void* fcb1 = d_in[36];
    const void* fcw2 = d_in[37]; const void* fcb2 = d_in[38];

    char* ws = (char*)d_ws;
    size_t off = 0;
    auto alloc = [&](size_t bytes) {
        char* p = ws + off;
        off = (off + bytes + 255) & ~(size_t)255;
        return p;
    };
    int*   FLAG = (int*)alloc(256);
    float* SACT = (float*)alloc(3 * 1536 * 4);
    float* E6   = (float*)alloc((size_t)3 * SIX * 4);
    float* EC   = (float*)alloc((size_t)3 * SIX * 4);
    bf16* NH  = (bf16*)alloc((size_t)TOTAL * DIM * 2);
    bf16* NE  = (bf16*)alloc((size_t)ENCR * DIM * 2);
    bf16* Qb  = (bf16*)alloc((size_t)TOTAL * DIM * 2);
    bf16* Kb  = (bf16*)alloc((size_t)TOTAL * DIM * 2);
    bf16* Vb  = (bf16*)alloc((size_t)TOTAL * DIM * 2);
    bf16* EQb = (bf16*)alloc((size_t)ENCR * DIM * 2);
    bf16* EKb = (bf16*)alloc((size_t)ENCR * DIM * 2);
    bf16* EVb = (bf16*)alloc((size_t)ENCR * DIM * 2);
    bf16* VJT = (bf16*)alloc((size_t)24 * 64 * (640 + 1152 + 1664) * 2);
    bf16* FF1  = (bf16*)alloc((size_t)TOTAL * INNER * 2);
    bf16* FFC1 = (bf16*)alloc((size_t)ENCR * INNER * 2);
    // transposed weights
    const size_t SQ = (size_t)DIM * DIM;          // 1536*1536
    const size_t RC = (size_t)DIM * INNER;        // 1536*6144
    bf16* WQKVT  = (bf16*)alloc(3 * SQ * 2);      // wqT|wkT|wvT  rows 0..4607
    bf16* WAQKVT = (bf16*)alloc(3 * SQ * 2);
    bf16* WOT    = (bf16*)alloc(SQ * 2);
    bf16* WAOT   = (bf16*)alloc(SQ * 2);
    bf16* FFW1T  = (bf16*)alloc(RC * 2);          // [6144][1536]
    bf16* FFW2T  = (bf16*)alloc(RC * 2);          // [1536][6144]
    bf16* FCW1T  = (bf16*)alloc(RC * 2);
    bf16* FCW2T  = (bf16*)alloc(RC * 2);
    bool useT = (off <= ws_size);

    // 0. dtype probe
    probe_kernel<<<1, 256, 0, stream>>>((const unsigned short*)ada_w, FLAG);

    // 0b. weight transposes
    if (useT) {
        dim3 gsq(24, 24), g16(96, 24), g61(24, 96);
        wt_kernel<<<gsq, 256, 0, stream>>>(wq,  WQKVT,           DIM, DIM, FLAG);
        wt_kernel<<<gsq, 256, 0, stream>>>(wk,  WQKVT + SQ,      DIM, DIM, FLAG);
        wt_kernel<<<gsq, 256, 0, stream>>>(wv,  WQKVT + 2 * SQ,  DIM, DIM, FLAG);
        wt_kernel<<<gsq, 256, 0, stream>>>(waq, WAQKVT,          DIM, DIM, FLAG);
        wt_kernel<<<gsq, 256, 0, stream>>>(wak, WAQKVT + SQ,     DIM, DIM, FLAG);
        wt_kernel<<<gsq, 256, 0, stream>>>(wav, WAQKVT + 2 * SQ, DIM, DIM, FLAG);
        wt_kernel<<<gsq, 256, 0, stream>>>(wo,  WOT,  DIM, DIM, FLAG);
        wt_kernel<<<gsq, 256, 0, stream>>>(wao, WAOT, DIM, DIM, FLAG);
        wt_kernel<<<g16, 256, 0, stream>>>(ffw1, FFW1T, DIM, INNER, FLAG);
        wt_kernel<<<g61, 256, 0, stream>>>(ffw2, FFW2T, INNER, DIM, FLAG);
        wt_kernel<<<g16, 256, 0, stream>>>(fcw1, FCW1T, DIM, INNER, FLAG);
        wt_kernel<<<g61, 256, 0, stream>>>(fcw2, FCW2T, INNER, DIM, FLAG);
    }

    // 1. AdaLN tables
    silu_kernel<<<18, 256, 0, stream>>>(temb, SACT, FLAG);
    ada_kernel<<<144, 256, 0, stream>>>(SACT, ada_w, ada_b, E6, FLAG);
    ada_kernel<<<144, 256, 0, stream>>>(SACT, ada_cw, ada_cb, EC, FLAG);

    // 2. LN + modulate (msa)
    ln_mod_kernel<<<TOTAL, 256, 0, stream>>>(hid, E6, NH, 0, 1, 0, 1, FLAG);
    ln_mod_kernel<<<ENCR, 256, 0, stream>>>(enc, EC, NE, 0, 1, 1, 1, FLAG);

    // 3. QKV projections
    if (useT) {
        gemm_t_kernel<<<dim3(36, 24), 256, 0, stream>>>((const short*)NH, (const short*)WQKVT,
            bq, bk, bv, Qb, Kb, Vb, DIM, DIM, 0, FLAG);
        gemm_t_kernel<<<dim3(36, 3), 256, 0, stream>>>((const short*)NE, (const short*)WAQKVT,
            baq, bak, bav, EQb, EKb, EVb, DIM, DIM, 0, FLAG);
    } else {
        dim3 gh(12, 24), ge(12, 3);
        gemm_kernel<<<gh, 256, 0, stream>>>((const short*)NH, wq, bq, Qb, TOTAL, DIM, DIM, 0, FLAG);
        gemm_kernel<<<gh, 256, 0, stream>>>((const short*)NH, wk, bk, Kb, TOTAL, DIM, DIM, 0, FLAG);
        gemm_kernel<<<gh, 256, 0, stream>>>((const short*)NH, wv, bv, Vb, TOTAL, DIM, DIM, 0, FLAG);
        gemm_kernel<<<ge, 256, 0, stream>>>((const short*)NE, waq, baq, EQb, ENCR, DIM, DIM, 0, FLAG);
        gemm_kernel<<<ge, 256, 0, stream>>>((const short*)NE, wak, bak, EKb, ENCR, DIM, DIM, 0, FLAG);
        gemm_kernel<<<ge, 256, 0, stream>>>((const short*)NE, wav, bav, EVb, ENCR, DIM, DIM, 0, FLAG);
    }

    // 4. per-head RMSNorm on q/k, then RoPE
    rms_kernel<<<(TOTAL * HEADS) / 4, 256, 0, stream>>>(Qb, nq_w, FLAG);
    rms_kernel<<<(TOTAL * HEADS) / 4, 256, 0, stream>>>(Kb, nk_w, FLAG);
    rms_kernel<<<(ENCR * HEADS) / 4, 256, 0, stream>>>(EQb, naq_w, FLAG);
    rms_kernel<<<(ENCR * HEADS) / 4, 256, 0, stream>>>(EKb, nak_w, FLAG);
    rope_kernel<<<(TOTAL * HEADS * 32) / 256, 256, 0, stream>>>(Qb, rope0, rope1, rope2, 0, FLAG);
    rope_kernel<<<(TOTAL * HEADS * 32) / 256, 256, 0, stream>>>(Kb, rope0, rope1, rope2, 0, FLAG);
    rope_kernel<<<(ENCR * HEADS * 32) / 256, 256, 0, stream>>>(EQb, rope0, rope1, rope2, 1, FLAG);
    rope_kernel<<<(ENCR * HEADS * 32) / 256, 256, 0, stream>>>(EKb, rope0, rope1, rope2, 1, FLAG);

    // 4b. V joint-transpose for PV B-fragments
    vjt_kernel<<<1296, 256, 0, stream>>>(Vb, EVb, VJT);

    // 5. MFMA flash attention (writes ATT_H->NH, ATT_E->NE)
    attn_mfma_kernel<<<1296, 256, 0, stream>>>(Qb, Kb, EQb, EKb, VJT, encv, NH, NE);

    // 6. output projections (PROJ_H->Qb, PROJ_E->EQb)
    if (useT) {
        gemm_t_kernel<<<dim3(12, 24), 256, 0, stream>>>((const short*)NH, (const short*)WOT,
            bo, bo, bo, Qb, Qb, Qb, DIM, DIM, 0, FLAG);
        gemm_t_kernel<<<dim3(12, 3), 256, 0, stream>>>((const short*)NE, (const short*)WAOT,
            bao, bao, bao, EQb, EQb, EQb, DIM, DIM, 0, FLAG);
    } else {
        dim3 gh(12, 24), ge(12, 3);
        gemm_kernel<<<gh, 256, 0, stream>>>((const short*)NH, wo, bo, Qb, TOTAL, DIM, DIM, 0, FLAG);
        gemm_kernel<<<ge, 256, 0, stream>>>((const short*)NE, wao, bao, EQb, ENCR, DIM, DIM, 0, FLAG);
    }

    // 7. gated residual #1 (H1->Kb, E1->EKb)
    resid_kernel<<<(TOTAL * DIM) / 256, 256, 0, stream>>>(hid, Qb, E6, 2, 0, Kb, 0, 1, 0, FLAG);
    resid_kernel<<<(ENCR * DIM) / 256, 256, 0, stream>>>(enc, EQb, EC, 2, 1, EKb, 0, 1, 0, FLAG);

    // 8. LN + modulate (mlp)
    ln_mod_kernel<<<TOTAL, 256, 0, stream>>>(Kb, E6, Vb, 3, 4, 0, 0, FLAG);
    ln_mod_kernel<<<ENCR, 256, 0, stream>>>(EKb, EC, EVb, 3, 4, 1, 0, FLAG);

    // 9. FFN
    if (useT) {
        gemm_t_kernel<<<dim3(48, 24), 256, 0, stream>>>((const short*)Vb, (const short*)FFW1T,
            ffb1, ffb1, ffb1, FF1, FF1, FF1, INNER, DIM, 1, FLAG);
        gemm_t_kernel<<<dim3(48, 3), 256, 0, stream>>>((const short*)EVb, (const short*)FCW1T,
            fcb1, fcb1, fcb1, FFC1, FFC1, FFC1, INNER, DIM, 1, FLAG);
        gemm_t_kernel<<<dim3(12, 24), 256, 0, stream>>>((const short*)FF1, (const short*)FFW2T,
            ffb2, ffb2, ffb2, NH, NH, NH, DIM, INNER, 0, FLAG);
        gemm_t_kernel<<<dim3(12, 3), 256, 0, stream>>>((const short*)FFC1, (const short*)FCW2T,
            fcb2, fcb2, fcb2, NE, NE, NE, DIM, INNER, 0, FLAG);
    } else {
        dim3 gh(12, 24), ge(12, 3), gf1(48, 24), gf1e(48, 3);
        gemm_kernel<<<gf1, 256, 0, stream>>>((const short*)Vb, ffw1, ffb1, FF1, TOTAL, INNER, DIM, 1, FLAG);
        gemm_kernel<<<gf1e, 256, 0, stream>>>((const short*)EVb, fcw1, fcb1, FFC1, ENCR, INNER, DIM, 1, FLAG);
        gemm_kernel<<<gh, 256, 0, stream>>>((const short*)FF1, ffw2, ffb2, NH, TOTAL, DIM, INNER, 0, FLAG);
        gemm_kernel<<<ge, 256, 0, stream>>>((const short*)FFC1, fcw2, fcb2, NE, ENCR, DIM, INNER, 0, FLAG);
    }

    // 10. gated residual #2 -> outputs (e first, then h)
    resid_kernel<<<(ENCR * DIM) / 256, 256, 0, stream>>>(EKb, NE, EC, 5, 1, d_out, 0, 0, 1, FLAG);
    resid_kernel<<<(TOTAL * DIM) / 256, 256, 0, stream>>>(Kb, NH, E6, 5, 0, d_out,
                                                          (size_t)ENCR * DIM, 0, 1, FLAG);
}